// Round 3
// baseline (209.561 us; speedup 1.0000x reference)
//
#include <hip/hip_runtime.h>

// GlobalAttention fused kernel for MI355X.  (Round 3 resubmission — rounds 0-2
// never reached hardware: GPUAcquisitionTimeout.)
// Reference: alpha = softmax_over_all(V·w_v + hid_term)  [hid_term drops: softmax shift-invariant]
//            attn  = sum_p alpha_p * V[p,:]
//            out   = relu([inp, attn] @ ctx_w^T + ctx_b)
// Single pass over V (134 MB) with fused exp-weighted accumulation.

#define HDIM 512
#define NPOS 65536   // 256*256

__device__ __forceinline__ float wave_sum(float v) {
#pragma unroll
    for (int m = 32; m >= 1; m >>= 1) v += __shfl_xor(v, m, 64);
    return v;
}

// K1: per-block partial of (sum_p exp(alpha_p) * V[p][k], sum_p exp(alpha_p)).
// ws1 layout: [B][513]  (k = 0..511 acc, k = 512 is the exp-sum)
__global__ __launch_bounds__(256, 4)
void k1_partial(const float* __restrict__ V, const float* __restrict__ att_w,
                float* __restrict__ ws1, int B) {
    const int tid  = threadIdx.x;
    const int lane = tid & 63;
    const int wid  = tid >> 6;          // 0..3
    const int b    = blockIdx.x;
    const int gw   = b * 4 + wid;       // global wave id
    const int W    = B * 4;             // total waves
    const int niter = NPOS / W;         // exact: B is a power of two >= 64

    // w_v fragment: this lane owns k = lane*8 .. lane*8+7
    const float* wvp = att_w + HDIM + lane * 8;
    const float4 wv0 = *reinterpret_cast<const float4*>(wvp);
    const float4 wv1 = *reinterpret_cast<const float4*>(wvp + 4);

    float acc[8] = {0.f,0.f,0.f,0.f,0.f,0.f,0.f,0.f};
    float lsum = 0.f;

#pragma unroll 2
    for (int it = 0; it < niter; ++it) {
        const int p = gw + it * W;      // consecutive waves hit adjacent 2KB rows
        const float* vp = V + (size_t)p * HDIM + lane * 8;
        const float4 a0 = *reinterpret_cast<const float4*>(vp);
        const float4 a1 = *reinterpret_cast<const float4*>(vp + 4);
        float d = a0.x*wv0.x + a0.y*wv0.y + a0.z*wv0.z + a0.w*wv0.w;
        d      += a1.x*wv1.x + a1.y*wv1.y + a1.z*wv1.z + a1.w*wv1.w;
        d = wave_sum(d);                // all lanes get full dot
        const float e = __expf(d);      // no max-shift needed: |alpha| ~ 2
        lsum += e;
        acc[0] += e*a0.x; acc[1] += e*a0.y; acc[2] += e*a0.z; acc[3] += e*a0.w;
        acc[4] += e*a1.x; acc[5] += e*a1.y; acc[6] += e*a1.z; acc[7] += e*a1.w;
    }

    __shared__ float lds[4][HDIM];
    __shared__ float ldsl[4];
#pragma unroll
    for (int j = 0; j < 8; ++j) lds[wid][lane*8 + j] = acc[j];
    if (lane == 0) ldsl[wid] = lsum;    // lsum is wave-uniform
    __syncthreads();

    const float s0 = lds[0][tid]       + lds[1][tid]       + lds[2][tid]       + lds[3][tid];
    const float s1 = lds[0][tid + 256] + lds[1][tid + 256] + lds[2][tid + 256] + lds[3][tid + 256];
    float* dst = ws1 + (size_t)b * 513;
    dst[tid]       = s0;                // coalesced block-partial write
    dst[tid + 256] = s1;
    if (tid == 0) dst[512] = ldsl[0] + ldsl[1] + ldsl[2] + ldsl[3];
}

// K2: column-sum of the B partials. One wave per k (513 columns).
__global__ __launch_bounds__(256)
void k2_combine(const float* __restrict__ ws1, float* __restrict__ ws2, int B) {
    const int lane = threadIdx.x & 63;
    const int wid  = threadIdx.x >> 6;
    const int k = blockIdx.x * 4 + wid;
    if (k > 512) return;
    float s = 0.f;
    for (int bb = lane; bb < B; bb += 64) s += ws1[(size_t)bb * 513 + k];
    s = wave_sum(s);
    if (lane == 0) ws2[k] = s;          // ws2[512] = L (softmax denominator)
}

// K3: out[r] = relu( sum_c cat[c]*ctx_w[r,c] + ctx_b[r] ), cat = [inp, attn_raw/L]
__global__ __launch_bounds__(256)
void k3_fc(const float* __restrict__ inp, const float* __restrict__ ctx_w,
           const float* __restrict__ ctx_b, const float* __restrict__ ws2,
           float* __restrict__ out) {
    const int lane = threadIdx.x & 63;
    const int wid  = threadIdx.x >> 6;
    const int r = blockIdx.x * 4 + wid;   // 0..511
    const float invL = 1.0f / ws2[512];
    const int cbase = lane * 16;          // lane covers c = cbase..cbase+15

    float4 c0, c1, c2, c3;
    if (lane < 32) {                      // c < 512: from inp
        const float* p = inp + cbase;
        c0 = *reinterpret_cast<const float4*>(p);
        c1 = *reinterpret_cast<const float4*>(p + 4);
        c2 = *reinterpret_cast<const float4*>(p + 8);
        c3 = *reinterpret_cast<const float4*>(p + 12);
    } else {                              // c >= 512: attn = raw/L
        const float* p = ws2 + (cbase - HDIM);
        c0 = *reinterpret_cast<const float4*>(p);
        c1 = *reinterpret_cast<const float4*>(p + 4);
        c2 = *reinterpret_cast<const float4*>(p + 8);
        c3 = *reinterpret_cast<const float4*>(p + 12);
        c0.x *= invL; c0.y *= invL; c0.z *= invL; c0.w *= invL;
        c1.x *= invL; c1.y *= invL; c1.z *= invL; c1.w *= invL;
        c2.x *= invL; c2.y *= invL; c2.z *= invL; c2.w *= invL;
        c3.x *= invL; c3.y *= invL; c3.z *= invL; c3.w *= invL;
    }

    const float* w = ctx_w + (size_t)r * 1024 + cbase;
    const float4 w0 = *reinterpret_cast<const float4*>(w);
    const float4 w1 = *reinterpret_cast<const float4*>(w + 4);
    const float4 w2 = *reinterpret_cast<const float4*>(w + 8);
    const float4 w3 = *reinterpret_cast<const float4*>(w + 12);

    float d = c0.x*w0.x + c0.y*w0.y + c0.z*w0.z + c0.w*w0.w;
    d      += c1.x*w1.x + c1.y*w1.y + c1.z*w1.z + c1.w*w1.w;
    d      += c2.x*w2.x + c2.y*w2.y + c2.z*w2.z + c2.w*w2.w;
    d      += c3.x*w3.x + c3.y*w3.y + c3.z*w3.z + c3.w*w3.w;
    d = wave_sum(d);
    if (lane == 0) out[r] = fmaxf(d + ctx_b[r], 0.0f);
}

extern "C" void kernel_launch(void* const* d_in, const int* in_sizes, int n_in,
                              void* d_out, int out_size, void* d_ws, size_t ws_size,
                              hipStream_t stream) {
    const float* inp   = (const float*)d_in[0];
    // d_in[1] = hid      : unused (softmax shift-invariance)
    const float* V     = (const float*)d_in[2];
    const float* att_w = (const float*)d_in[3];
    // d_in[4] = att_b    : unused (softmax shift-invariance)
    const float* ctx_w = (const float*)d_in[5];
    const float* ctx_b = (const float*)d_in[6];
    float* out = (float*)d_out;
    float* ws  = (float*)d_ws;

    int B = 1024;                                    // K1 blocks (power of two)
    while (B > 64 && ((size_t)B * 513 + 513) * sizeof(float) > ws_size) B >>= 1;

    float* ws1 = ws;                                 // [B][513] partials
    float* ws2 = ws + (size_t)B * 513;               // [513] combined (raw attn + L)

    k1_partial<<<dim3(B),   dim3(256), 0, stream>>>(V, att_w, ws1, B);
    k2_combine<<<dim3(129), dim3(256), 0, stream>>>(ws1, ws2, B);
    k3_fc     <<<dim3(128), dim3(256), 0, stream>>>(inp, ctx_w, ctx_b, ws2, out);
}